// Round 6
// baseline (218.305 us; speedup 1.0000x reference)
//
#include <hip/hip_runtime.h>
#include <cmath>

typedef unsigned short u16;
typedef unsigned int   u32;
typedef __attribute__((ext_vector_type(8))) __bf16 bf16x8;
typedef __attribute__((ext_vector_type(2))) __bf16 bf16x2;
typedef __attribute__((ext_vector_type(4))) float  f32x4;

constexpr int BB = 2, SEQ = 2048, CH = 1024, NH = 16, DH = 64;

__device__ inline u16 f2bf(float f) {            // RNE fp32 -> bf16
    u32 u = __builtin_bit_cast(u32, f);
    u += 0x7FFF + ((u >> 16) & 1);
    return (u16)(u >> 16);
}
__device__ inline float bf2f(u16 b) { return __builtin_bit_cast(float, (u32)b << 16); }
__device__ inline u32 pkbf(float a, float b) {   // pack two RNE bf16 into u32
#if __has_builtin(__builtin_amdgcn_cvt_pk_bf16_f32)
    bf16x2 r = __builtin_amdgcn_cvt_pk_bf16_f32(a, b);
    return __builtin_bit_cast(u32, r);
#else
    return (u32)f2bf(a) | ((u32)f2bf(b) << 16);
#endif
}
__device__ inline float fexp2(float x) {
#if __has_builtin(__builtin_amdgcn_exp2f)
    return __builtin_amdgcn_exp2f(x);
#else
    return exp2f(x);
#endif
}

__device__ inline void gld_lds16(const void* g, void* l) {
    __builtin_amdgcn_global_load_lds((const __attribute__((address_space(1))) void*)g,
                                     (__attribute__((address_space(3))) void*)l, 16, 0, 0);
}
__device__ inline f32x4 mfma16(bf16x8 a, bf16x8 b, f32x4 c) {
    return __builtin_amdgcn_mfma_f32_16x16x32_bf16(a, b, c, 0, 0, 0);
}
__device__ inline bf16x8 ld_frag(const u16* p) {
    return __builtin_bit_cast(bf16x8, *(const uint4*)p);
}

// ---------------------------------------------------------------------------
// fp32 -> bf16 conversion for x, qkv_w, proj_w
// ---------------------------------------------------------------------------
__global__ __launch_bounds__(256) void convert_kernel(const float* __restrict__ x,
                                                      const float* __restrict__ wq,
                                                      const float* __restrict__ wp,
                                                      u16* __restrict__ xb,
                                                      u16* __restrict__ wqb,
                                                      u16* __restrict__ wpb) {
    const int q = blockIdx.x * 256 + threadIdx.x;   // quad index
    const float* src; u16* dst; int idx;
    if (q < 1048576)            { src = x;  dst = xb;  idx = q; }
    else if (q < 1048576+786432){ src = wq; dst = wqb; idx = q - 1048576; }
    else                        { src = wp; dst = wpb; idx = q - 1048576 - 786432; }
    float4 v = *(const float4*)(src + (size_t)idx * 4);
    ushort4 o; o.x = f2bf(v.x); o.y = f2bf(v.y); o.z = f2bf(v.z); o.w = f2bf(v.w);
    *(ushort4*)(dst + (size_t)idx * 4) = o;
}

// ---------------------------------------------------------------------------
// Fused QKV GEMM + RoPE + head-major repack.
// C[m,n] = sum_k x_bf[m,k] * qkv_w_bf[n,k], then per block-region:
//   q (n<1024):  rope (pos[...,0]/[...,1]) * Dh^-0.5*log2e -> Qb[bh][n][d]
//   k (n<2048):  rope                                       -> Kb[bh][n][d]
//   v:           transpose via per-wave LDS                 -> Vt[bh][d][n]
// Each wave's 64 columns = exactly one head; lane holds rotate pair
// (d, d+16) in (acc[mi][0],acc[mi][1]) and (acc[mi][2],acc[mi][3]).
// ---------------------------------------------------------------------------
__global__ __launch_bounds__(256) void gemm_qkv_rope(const u16* __restrict__ A,
                                                     const u16* __restrict__ Bw,
                                                     const int* __restrict__ pos,
                                                     u16* __restrict__ Qb,
                                                     u16* __restrict__ Kb,
                                                     u16* __restrict__ Vt) {
    __shared__ u16 smem[18432];          // staging [0,8192); V-transpose 4 x 4608
    u16* As = smem;
    u16* Bs = smem + 4096;
    const int t = threadIdx.x, lane = t & 63, w = t >> 6;
    const int l15 = lane & 15, quad = lane >> 4;
    const int wm = w >> 1, wn = w & 1;
    const int m0 = blockIdx.y * 128, n0 = blockIdx.x * 128;
    const int K = CH, N = 3 * CH;

    const int row0 = t >> 2, v0 = t & 3;
    const int gi0 = (v0 - (row0 >> 1)) & 3;
    const int row1 = row0 + 64;
    const int gi1 = (v0 - (row1 >> 1)) & 3;

    f32x4 acc[4][4] = {};
    for (int k0 = 0; k0 < K; k0 += 32) {
        __syncthreads();
        gld_lds16(A  + (size_t)(m0 + row0) * K + k0 + gi0 * 8, As + t * 8);
        gld_lds16(A  + (size_t)(m0 + row1) * K + k0 + gi1 * 8, As + 2048 + t * 8);
        gld_lds16(Bw + (size_t)(n0 + row0) * K + k0 + gi0 * 8, Bs + t * 8);
        gld_lds16(Bw + (size_t)(n0 + row1) * K + k0 + gi1 * 8, Bs + 2048 + t * 8);
        __syncthreads();
        bf16x8 af[4], bfv[4];
#pragma unroll
        for (int mi = 0; mi < 4; ++mi) {
            const int r = wm * 64 + mi * 16 + l15;
            af[mi] = ld_frag(As + (r * 4 + ((quad + (r >> 1)) & 3)) * 8);
        }
#pragma unroll
        for (int nj = 0; nj < 4; ++nj) {
            const int r = wn * 64 + nj * 16 + l15;
            bfv[nj] = ld_frag(Bs + (r * 4 + ((quad + (r >> 1)) & 3)) * 8);
        }
#pragma unroll
        for (int mi = 0; mi < 4; ++mi)
#pragma unroll
            for (int nj = 0; nj < 4; ++nj)
                acc[mi][nj] = mfma16(af[mi], bfv[nj], acc[mi][nj]);
    }

    const int reg = n0 >> 10;                      // 0=q, 1=k, 2=v (block-uniform)
    const int h   = ((n0 & 1023) >> 6) + wn;       // wave's head
    if (reg < 2) {
        // RoPE on fp32 accumulator, then scatter to (bh, n, d) bf16.
        const float fr = exp2f(-(float)l15 * 0.41524101186092f);  // 100^(-l15/16)
        const float scale = reg ? 1.0f : 0.18033688011112042f;    // Dh^-.5 * log2e
        u16* dst = reg ? Kb : Qb;
#pragma unroll
        for (int mi = 0; mi < 4; ++mi) {
#pragma unroll
            for (int r = 0; r < 4; ++r) {
                const int m = m0 + wm * 64 + mi * 16 + quad * 4 + r;  // b*SEQ+n
                const int bh = (m >> 11) * NH + h;
                const int n  = m & 2047;
                float sy, cy, sx, cx;
                sincosf((float)pos[m * 2]     * fr, &sy, &cy);
                sincosf((float)pos[m * 2 + 1] * fr, &sx, &cx);
                cy *= scale; sy *= scale; cx *= scale; sx *= scale;
                const float x1 = acc[mi][0][r], x2 = acc[mi][1][r];
                const float y1 = acc[mi][2][r], y2 = acc[mi][3][r];
                u16* p = dst + ((size_t)bh * SEQ + n) * 64 + l15;
                p[0]  = f2bf(x1 * cy - x2 * sy);
                p[16] = f2bf(x1 * sy + x2 * cy);
                p[32] = f2bf(y1 * cx - y2 * sx);
                p[48] = f2bf(y1 * sx + y2 * cx);
            }
        }
    } else {
        // V: per-wave 64x64 transpose through LDS (stride 72 u16, 16B-aligned
        // rows, <=2-way banks), then coalesced 16B writes to Vt[bh][d][n].
        __syncthreads();                 // all staging reads finished block-wide
        u16* T = smem + w * 4608;
#pragma unroll
        for (int mi = 0; mi < 4; ++mi)
#pragma unroll
            for (int nj = 0; nj < 4; ++nj)
#pragma unroll
                for (int r = 0; r < 4; ++r)
                    T[(nj * 16 + l15) * 72 + mi * 16 + quad * 4 + r] =
                        f2bf(acc[mi][nj][r]);
        // same-wave LDS RAW: DS ops complete in order, no barrier needed
        const int bh = (m0 >> 11) * NH + h;
        const int nbase = (m0 & 2047) + wm * 64;
        u16* gdst = Vt + ((size_t)bh * 64 + lane) * SEQ + nbase;
#pragma unroll
        for (int j = 0; j < 8; ++j)
            *(uint4*)(gdst + j * 8) = *(const uint4*)(T + lane * 72 + j * 8);
    }
}

// ---------------------------------------------------------------------------
// bf16 MFMA GEMM (proj): C[m,n] = sum_k A[m,k]*Bw[n,k] + bias[n], fp32 out.
// ---------------------------------------------------------------------------
__global__ __launch_bounds__(256) void gemm_bf16(const u16* __restrict__ A,
                                                 const u16* __restrict__ Bw,
                                                 const float* __restrict__ bias,
                                                 float* __restrict__ C,
                                                 int M, int N, int K) {
    __shared__ u16 As[128 * 32];
    __shared__ u16 Bs[128 * 32];
    const int t = threadIdx.x, lane = t & 63, w = t >> 6;
    const int l15 = lane & 15, quad = lane >> 4;
    const int wm = w >> 1, wn = w & 1;
    const int m0 = blockIdx.y * 128, n0 = blockIdx.x * 128;

    const int row0 = t >> 2, v0 = t & 3;
    const int gi0 = (v0 - (row0 >> 1)) & 3;
    const int row1 = row0 + 64;
    const int gi1 = (v0 - (row1 >> 1)) & 3;

    f32x4 acc[4][4] = {};
    for (int k0 = 0; k0 < K; k0 += 32) {
        __syncthreads();
        gld_lds16(A  + (size_t)(m0 + row0) * K + k0 + gi0 * 8, As + t * 8);
        gld_lds16(A  + (size_t)(m0 + row1) * K + k0 + gi1 * 8, As + 2048 + t * 8);
        gld_lds16(Bw + (size_t)(n0 + row0) * K + k0 + gi0 * 8, Bs + t * 8);
        gld_lds16(Bw + (size_t)(n0 + row1) * K + k0 + gi1 * 8, Bs + 2048 + t * 8);
        __syncthreads();
        bf16x8 af[4], bfv[4];
#pragma unroll
        for (int mi = 0; mi < 4; ++mi) {
            const int r = wm * 64 + mi * 16 + l15;
            af[mi] = ld_frag(As + (r * 4 + ((quad + (r >> 1)) & 3)) * 8);
        }
#pragma unroll
        for (int nj = 0; nj < 4; ++nj) {
            const int r = wn * 64 + nj * 16 + l15;
            bfv[nj] = ld_frag(Bs + (r * 4 + ((quad + (r >> 1)) & 3)) * 8);
        }
#pragma unroll
        for (int mi = 0; mi < 4; ++mi)
#pragma unroll
            for (int nj = 0; nj < 4; ++nj)
                acc[mi][nj] = mfma16(af[mi], bfv[nj], acc[mi][nj]);
    }
#pragma unroll
    for (int mi = 0; mi < 4; ++mi)
#pragma unroll
        for (int nj = 0; nj < 4; ++nj) {
            const int n = n0 + wn * 64 + nj * 16 + l15;
            const float bv = bias[n];
#pragma unroll
            for (int r = 0; r < 4; ++r) {
                const int m = m0 + wm * 64 + mi * 16 + quad * 4 + r;
                C[(size_t)m * N + n] = acc[mi][nj][r] + bv;
            }
        }
}

// ---------------------------------------------------------------------------
// Flash attention, bf16 MFMA, softmax-lite (exp2 only, no max; additive
// split-K). Row sums computed by MFMA against a ones-fragment (l = P @ 1),
// so the inner loop has zero scalar reductions and the epilogue no shuffles.
// ---------------------------------------------------------------------------
__global__ __launch_bounds__(256, 4) void attn_mfma(const u16* __restrict__ Qb,
                                                    const u16* __restrict__ Kb,
                                                    const u16* __restrict__ Vt,
                                                    u16* __restrict__ Opart,
                                                    float* __restrict__ lpart) {
    __shared__ u16 Ks[64 * 64];
    __shared__ u16 Vs[64 * 64];
    __shared__ u16 Ps[128 * 72];
    const int t = threadIdx.x, lane = t & 63, w = t >> 6;
    const int l15 = lane & 15, quad = lane >> 4;
    const int bh = blockIdx.y;
    const int q0 = blockIdx.x * 128;
    const int z  = blockIdx.z;

    const int rowA = t >> 3, vA = t & 7;
    const int giA = (vA - rowA) & 7;
    const int rowB = rowA + 32;
    const int giB = (vA - rowB) & 7;

    const size_t kbase = (size_t)bh * SEQ * 64;   // Kb: [bh][n][d]
    const size_t vbase = (size_t)bh * 64 * SEQ;   // Vt: [bh][d][n]

    const uint4 ones_u = {0x3F803F80u, 0x3F803F80u, 0x3F803F80u, 0x3F803F80u};
    const bf16x8 onesf = __builtin_bit_cast(bf16x8, ones_u);

    bf16x8 aq[2][2];
#pragma unroll
    for (int mi = 0; mi < 2; ++mi)
#pragma unroll
        for (int ks = 0; ks < 2; ++ks)
            aq[mi][ks] = ld_frag(Qb + ((size_t)bh * SEQ + q0 + w * 32 + mi * 16 + l15) * 64
                                 + ks * 32 + quad * 8);

    f32x4 oacc[2][4] = {};
    f32x4 lacc[2] = {};

    for (int kt = 0; kt < 16; ++kt) {
        const int k0 = z * 1024 + kt * 64;
        __syncthreads();
        gld_lds16(Kb + kbase + (size_t)(k0 + rowA) * 64 + giA * 8, Ks + t * 8);
        gld_lds16(Kb + kbase + (size_t)(k0 + rowB) * 64 + giB * 8, Ks + 2048 + t * 8);
        gld_lds16(Vt + vbase + (size_t)rowA * SEQ + k0 + giA * 8, Vs + t * 8);
        gld_lds16(Vt + vbase + (size_t)rowB * SEQ + k0 + giB * 8, Vs + 2048 + t * 8);
        __syncthreads();

        // S^T = K Q^T : lane holds (q = l15, k = nk*16 + quad*4 + r)
        f32x4 sacc[2][4] = {};
#pragma unroll
        for (int ks = 0; ks < 2; ++ks)
#pragma unroll
            for (int nk = 0; nk < 4; ++nk) {
                const int rK = nk * 16 + l15;
                const bf16x8 kf = ld_frag(Ks + (rK * 8 + (((ks * 4 + quad) + rK) & 7)) * 8);
                sacc[0][nk] = mfma16(kf, aq[0][ks], sacc[0][nk]);
                sacc[1][nk] = mfma16(kf, aq[1][ks], sacc[1][nk]);
            }

        // softmax-lite: p = exp2(s); pack pairs and store P rows to LDS
#pragma unroll
        for (int mi = 0; mi < 2; ++mi) {
            const int prow = (w * 32 + mi * 16 + l15) * 72;
#pragma unroll
            for (int nk = 0; nk < 4; ++nk) {
                const float p0 = fexp2(sacc[mi][nk][0]);
                const float p1 = fexp2(sacc[mi][nk][1]);
                const float p2 = fexp2(sacc[mi][nk][2]);
                const float p3 = fexp2(sacc[mi][nk][3]);
                uint2 pk; pk.x = pkbf(p0, p1); pk.y = pkbf(p2, p3);
                *(uint2*)&Ps[prow + nk * 16 + quad * 4] = pk;
            }
        }

        // O += P V ; l += P @ ones  (same-wave LDS RAW: DS in-order per wave)
#pragma unroll
        for (int ks = 0; ks < 2; ++ks) {
            const bf16x8 ap0 = ld_frag(Ps + (w * 32 + l15) * 72 + ks * 32 + quad * 8);
            const bf16x8 ap1 = ld_frag(Ps + (w * 32 + 16 + l15) * 72 + ks * 32 + quad * 8);
            lacc[0] = mfma16(ap0, onesf, lacc[0]);
            lacc[1] = mfma16(ap1, onesf, lacc[1]);
#pragma unroll
            for (int nj = 0; nj < 4; ++nj) {
                const int rV = nj * 16 + l15;
                const bf16x8 vf = ld_frag(Vs + (rV * 8 + (((ks * 4 + quad) + rV) & 7)) * 8);
                oacc[0][nj] = mfma16(ap0, vf, oacc[0][nj]);
                oacc[1][nj] = mfma16(ap1, vf, oacc[1][nj]);
            }
        }
    }

    // epilogue: lacc is in C-layout (row = quad*4+r, col replicated) — no shuffles
#pragma unroll
    for (int mi = 0; mi < 2; ++mi)
#pragma unroll
        for (int r = 0; r < 4; ++r) {
            const int qrow = q0 + w * 32 + mi * 16 + quad * 4 + r;
            if (l15 == 0)
                lpart[((size_t)z * 32 + bh) * SEQ + qrow] = lacc[mi][r];
            const size_t orow = (((size_t)z * 32 + bh) * SEQ + qrow) * 64;
#pragma unroll
            for (int nj = 0; nj < 4; ++nj)
                Opart[orow + nj * 16 + l15] = f2bf(oacc[mi][nj][r]);
        }
}

// ---------------------------------------------------------------------------
// Merge the two K-splits: O = (O1 + O2) / (l1 + l2), repack to (B,N,H*DH) bf16.
// ---------------------------------------------------------------------------
__global__ __launch_bounds__(256) void merge_kernel(const u16* __restrict__ Opart,
                                                    const float* __restrict__ lpart,
                                                    u16* __restrict__ Ob) {
    const int gid = blockIdx.x * 256 + threadIdx.x;     // 1,048,576 total
    const int d4 = gid & 15, q = (gid >> 4) & 2047, bh = gid >> 15;
    const size_t i1 = ((size_t)bh * SEQ + q) * 64 + d4 * 4;
    const size_t i2 = i1 + (size_t)32 * SEQ * 64;
    const float inv = 1.0f / (lpart[(size_t)bh * SEQ + q] +
                              lpart[(size_t)(32 + bh) * SEQ + q]);
    const ushort4 a = *(const ushort4*)(Opart + i1);
    const ushort4 b = *(const ushort4*)(Opart + i2);
    ushort4 o;
    o.x = f2bf((bf2f(a.x) + bf2f(b.x)) * inv);
    o.y = f2bf((bf2f(a.y) + bf2f(b.y)) * inv);
    o.z = f2bf((bf2f(a.z) + bf2f(b.z)) * inv);
    o.w = f2bf((bf2f(a.w) + bf2f(b.w)) * inv);
    const int b_ = bh >> 4, h = bh & 15;
    *(ushort4*)(Ob + ((size_t)(b_ * SEQ + q)) * CH + h * 64 + d4 * 4) = o;
}

// ---------------------------------------------------------------------------
// Workspace layout (u16 offsets; extent 29,360,128 u16 = 56.00 MiB, same
// total as the proven R2/R5 layouts):
//   [0         ..  4,194,304)  x_bf      -> attn_bf after qkv (merge out)
//   [4,194,304 ..  7,340,032)  wq_bf     -> lpart after qkv   (attn out)
//   [7,340,032 ..  8,388,608)  wp_bf     (live until proj)
//   [8,388,608 .. 12,582,912)  Qb
//   [12,582,912.. 16,777,216)  Kb
//   [16,777,216.. 20,971,520)  Vt
//   [20,971,520.. 29,360,128)  Opart (2 splits x 4.2M)
// ---------------------------------------------------------------------------
extern "C" void kernel_launch(void* const* d_in, const int* in_sizes, int n_in,
                              void* d_out, int out_size, void* d_ws, size_t ws_size,
                              hipStream_t stream) {
    const float* x      = (const float*)d_in[0];
    const int*   pos    = (const int*)d_in[1];
    const float* qkv_w  = (const float*)d_in[2];
    const float* proj_w = (const float*)d_in[3];
    const float* proj_b = (const float*)d_in[4];
    float* out = (float*)d_out;

    u16* ws = (u16*)d_ws;
    u16* x_bf    = ws;
    u16* attn_bf = ws;                          // aliases x_bf (dead after qkv)
    u16* wq_bf   = ws + 4194304;
    float* lpart = (float*)(ws + 4194304);      // aliases wq_bf (dead after qkv)
    u16* wp_bf   = ws + 7340032;
    u16* Qb      = ws + 8388608;
    u16* Kb      = ws + 12582912;
    u16* Vt      = ws + 16777216;
    u16* Opart   = ws + 20971520;

    const int M = BB * SEQ;  // 4096

    convert_kernel<<<8192, 256, 0, stream>>>(x, qkv_w, proj_w, x_bf, wq_bf, wp_bf);
    gemm_qkv_rope<<<dim3(3 * CH / 128, M / 128), 256, 0, stream>>>(
        x_bf, wq_bf, pos, Qb, Kb, Vt);
    attn_mfma<<<dim3(SEQ / 128, BB * NH, 2), 256, 0, stream>>>(Qb, Kb, Vt, Opart, lpart);
    merge_kernel<<<4096, 256, 0, stream>>>(Opart, lpart, attn_bf);
    gemm_bf16<<<dim3(CH / 128, M / 128), 256, 0, stream>>>(
        attn_bf, wp_bf, proj_b, out, M, CH, CH);
}

// Round 7
// 201.561 us; speedup vs baseline: 1.0831x; 1.0831x over previous
//
#include <hip/hip_runtime.h>
#include <cmath>

typedef unsigned short u16;
typedef unsigned int   u32;
typedef __attribute__((ext_vector_type(8))) __bf16 bf16x8;
typedef __attribute__((ext_vector_type(2))) __bf16 bf16x2;
typedef __attribute__((ext_vector_type(4))) float  f32x4;

constexpr int BB = 2, SEQ = 2048, CH = 1024, NH = 16, DH = 64;

__device__ inline u16 f2bf(float f) {            // RNE fp32 -> bf16
    u32 u = __builtin_bit_cast(u32, f);
    u += 0x7FFF + ((u >> 16) & 1);
    return (u16)(u >> 16);
}
__device__ inline float bf2f(u16 b) { return __builtin_bit_cast(float, (u32)b << 16); }
__device__ inline u32 pkbf(float a, float b) {   // pack two RNE bf16 into u32
#if __has_builtin(__builtin_amdgcn_cvt_pk_bf16_f32)
    bf16x2 r = __builtin_amdgcn_cvt_pk_bf16_f32(a, b);
    return __builtin_bit_cast(u32, r);
#else
    return (u32)f2bf(a) | ((u32)f2bf(b) << 16);
#endif
}
__device__ inline float fexp2(float x) {
#if __has_builtin(__builtin_amdgcn_exp2f)
    return __builtin_amdgcn_exp2f(x);
#else
    return exp2f(x);
#endif
}

__device__ inline void gld_lds16(const void* g, void* l) {
    __builtin_amdgcn_global_load_lds((const __attribute__((address_space(1))) void*)g,
                                     (__attribute__((address_space(3))) void*)l, 16, 0, 0);
}
__device__ inline f32x4 mfma16(bf16x8 a, bf16x8 b, f32x4 c) {
    return __builtin_amdgcn_mfma_f32_16x16x32_bf16(a, b, c, 0, 0, 0);
}
__device__ inline bf16x8 ld_frag(const u16* p) {
    return __builtin_bit_cast(bf16x8, *(const uint4*)p);
}

// ---------------------------------------------------------------------------
// fp32 -> bf16 conversion for x, qkv_w, proj_w + RoPE sin/cos table gen.
// Tables: tab[p*16+i] = (cos(p*f_i), sin(p*f_i)), f_i = 100^(-i/16), p in [0,64).
// tabq carries the extra Dh^-0.5 * log2(e) factor.
// ---------------------------------------------------------------------------
__global__ __launch_bounds__(256) void convert_kernel(const float* __restrict__ x,
                                                      const float* __restrict__ wq,
                                                      const float* __restrict__ wp,
                                                      u16* __restrict__ xb,
                                                      u16* __restrict__ wqb,
                                                      u16* __restrict__ wpb,
                                                      float2* __restrict__ tabq,
                                                      float2* __restrict__ tabk) {
    const int q = blockIdx.x * 256 + threadIdx.x;   // quad index
    if (q >= 2097152) {                             // table-gen tail: 1024 threads
        const int idx = q - 2097152;
        if (idx < 1024) {
            const int p = idx >> 4, i = idx & 15;
            const float f = exp2f(-(float)i * 0.41524101186092f);  // log2(100)/16
            float s, c;
            sincosf((float)p * f, &s, &c);
            tabk[idx] = make_float2(c, s);
            tabq[idx] = make_float2(c * 0.18033688011112042f,
                                    s * 0.18033688011112042f);
        }
        return;
    }
    const float* src; u16* dst; int idx;
    if (q < 1048576)            { src = x;  dst = xb;  idx = q; }
    else if (q < 1048576+786432){ src = wq; dst = wqb; idx = q - 1048576; }
    else                        { src = wp; dst = wpb; idx = q - 1048576 - 786432; }
    float4 v = *(const float4*)(src + (size_t)idx * 4);
    ushort4 o; o.x = f2bf(v.x); o.y = f2bf(v.y); o.z = f2bf(v.z); o.w = f2bf(v.w);
    *(ushort4*)(dst + (size_t)idx * 4) = o;
}

// ---------------------------------------------------------------------------
// Fused QKV GEMM + RoPE + head-major repack, double-buffered staging.
// K-loop: one barrier per iter; prefetch tile kt+1 via global_load_lds right
// after the barrier so the vmcnt(0) drain at the NEXT barrier waits on loads
// that already had a full compute phase in flight.
//   q (n<1024):  rope via tabq -> Qb[bh][n][d]
//   k (n<2048):  rope via tabk -> Kb[bh][n][d]
//   v:           64x64 transpose via per-wave LDS -> Vt[bh][d][n]
// ---------------------------------------------------------------------------
__global__ __launch_bounds__(256) void gemm_qkv_rope(const u16* __restrict__ A,
                                                     const u16* __restrict__ Bw,
                                                     const int* __restrict__ pos,
                                                     const float2* __restrict__ tabq,
                                                     const float2* __restrict__ tabk,
                                                     u16* __restrict__ Qb,
                                                     u16* __restrict__ Kb,
                                                     u16* __restrict__ Vt) {
    __shared__ u16 smem[18432];   // dbuf staging [0,16384); V-transpose reuses [0,18432)
    const int t = threadIdx.x, lane = t & 63, w = t >> 6;
    const int l15 = lane & 15, quad = lane >> 4;
    const int wm = w >> 1, wn = w & 1;
    const int m0 = blockIdx.y * 128, n0 = blockIdx.x * 128;
    const int K = CH;

    const int row0 = t >> 2, v0 = t & 3;
    const int gi0 = (v0 - (row0 >> 1)) & 3;
    const int row1 = row0 + 64;
    const int gi1 = (v0 - (row1 >> 1)) & 3;

    const u16* A0 = A  + (size_t)(m0 + row0) * K + gi0 * 8;
    const u16* A1 = A  + (size_t)(m0 + row1) * K + gi1 * 8;
    const u16* B0 = Bw + (size_t)(n0 + row0) * K + gi0 * 8;
    const u16* B1 = Bw + (size_t)(n0 + row1) * K + gi1 * 8;

    // prologue: stage tile 0 into buffer 0
    gld_lds16(A0, smem + t * 8);
    gld_lds16(A1, smem + 2048 + t * 8);
    gld_lds16(B0, smem + 8192 + t * 8);
    gld_lds16(B1, smem + 10240 + t * 8);

    f32x4 acc[4][4] = {};
    for (int kt = 0; kt < K / 32; ++kt) {
        __syncthreads();          // drains buffer(kt&1) loads; syncs prev compute
        const int cur = (kt & 1) * 4096;
        if (kt + 1 < K / 32) {
            const int off = (kt + 1) * 32;
            const int nxt = ((kt + 1) & 1) * 4096;
            gld_lds16(A0 + off, smem + nxt + t * 8);
            gld_lds16(A1 + off, smem + nxt + 2048 + t * 8);
            gld_lds16(B0 + off, smem + 8192 + nxt + t * 8);
            gld_lds16(B1 + off, smem + 8192 + nxt + 2048 + t * 8);
        }
        const u16* as = smem + cur;
        const u16* bs = smem + 8192 + cur;
        bf16x8 af[4], bfv[4];
#pragma unroll
        for (int mi = 0; mi < 4; ++mi) {
            const int r = wm * 64 + mi * 16 + l15;
            af[mi] = ld_frag(as + (r * 4 + ((quad + (r >> 1)) & 3)) * 8);
        }
#pragma unroll
        for (int nj = 0; nj < 4; ++nj) {
            const int r = wn * 64 + nj * 16 + l15;
            bfv[nj] = ld_frag(bs + (r * 4 + ((quad + (r >> 1)) & 3)) * 8);
        }
#pragma unroll
        for (int mi = 0; mi < 4; ++mi)
#pragma unroll
            for (int nj = 0; nj < 4; ++nj)
                acc[mi][nj] = mfma16(af[mi], bfv[nj], acc[mi][nj]);
    }

    const int reg = n0 >> 10;                      // 0=q, 1=k, 2=v (block-uniform)
    const int h   = ((n0 & 1023) >> 6) + wn;       // wave's head
    if (reg < 2) {
        const float2* tab = reg ? tabk : tabq;     // scale pre-folded into tabq
        u16* dst = reg ? Kb : Qb;
#pragma unroll
        for (int mi = 0; mi < 4; ++mi) {
#pragma unroll
            for (int r = 0; r < 4; ++r) {
                const int m = m0 + wm * 64 + mi * 16 + quad * 4 + r;  // b*SEQ+n
                const int bh = (m >> 11) * NH + h;
                const int n  = m & 2047;
                const int2 pp = *(const int2*)(pos + m * 2);
                const float2 ty = tab[pp.x * 16 + l15];
                const float2 tx = tab[pp.y * 16 + l15];
                const float x1 = acc[mi][0][r], x2 = acc[mi][1][r];
                const float y1 = acc[mi][2][r], y2 = acc[mi][3][r];
                u16* p = dst + ((size_t)bh * SEQ + n) * 64 + l15;
                p[0]  = f2bf(x1 * ty.x - x2 * ty.y);
                p[16] = f2bf(x1 * ty.y + x2 * ty.x);
                p[32] = f2bf(y1 * tx.x - y2 * tx.y);
                p[48] = f2bf(y1 * tx.y + y2 * tx.x);
            }
        }
    } else {
        // V: per-wave 64x64 transpose through LDS (stride 72 u16, 16B-aligned
        // rows, <=2-way banks), then coalesced 16B writes to Vt[bh][d][n].
        __syncthreads();                 // all staging reads finished block-wide
        u16* T = smem + w * 4608;
#pragma unroll
        for (int mi = 0; mi < 4; ++mi)
#pragma unroll
            for (int nj = 0; nj < 4; ++nj)
#pragma unroll
                for (int r = 0; r < 4; ++r)
                    T[(nj * 16 + l15) * 72 + mi * 16 + quad * 4 + r] =
                        f2bf(acc[mi][nj][r]);
        // same-wave LDS RAW: DS ops complete in order, no barrier needed
        const int bh = (m0 >> 11) * NH + h;
        const int nbase = (m0 & 2047) + wm * 64;
        u16* gdst = Vt + ((size_t)bh * 64 + lane) * SEQ + nbase;
#pragma unroll
        for (int j = 0; j < 8; ++j)
            *(uint4*)(gdst + j * 8) = *(const uint4*)(T + lane * 72 + j * 8);
    }
}

// ---------------------------------------------------------------------------
// bf16 MFMA GEMM (proj): C = A @ Bw^T + bias, fp32 out. Double-buffered.
// ---------------------------------------------------------------------------
__global__ __launch_bounds__(256) void gemm_bf16(const u16* __restrict__ A,
                                                 const u16* __restrict__ Bw,
                                                 const float* __restrict__ bias,
                                                 float* __restrict__ C,
                                                 int M, int N, int K) {
    __shared__ u16 smem[16384];
    const int t = threadIdx.x, lane = t & 63, w = t >> 6;
    const int l15 = lane & 15, quad = lane >> 4;
    const int wm = w >> 1, wn = w & 1;
    const int m0 = blockIdx.y * 128, n0 = blockIdx.x * 128;

    const int row0 = t >> 2, v0 = t & 3;
    const int gi0 = (v0 - (row0 >> 1)) & 3;
    const int row1 = row0 + 64;
    const int gi1 = (v0 - (row1 >> 1)) & 3;

    const u16* A0 = A  + (size_t)(m0 + row0) * K + gi0 * 8;
    const u16* A1 = A  + (size_t)(m0 + row1) * K + gi1 * 8;
    const u16* B0 = Bw + (size_t)(n0 + row0) * K + gi0 * 8;
    const u16* B1 = Bw + (size_t)(n0 + row1) * K + gi1 * 8;

    gld_lds16(A0, smem + t * 8);
    gld_lds16(A1, smem + 2048 + t * 8);
    gld_lds16(B0, smem + 8192 + t * 8);
    gld_lds16(B1, smem + 10240 + t * 8);

    f32x4 acc[4][4] = {};
    for (int kt = 0; kt < K / 32; ++kt) {
        __syncthreads();
        const int cur = (kt & 1) * 4096;
        if (kt + 1 < K / 32) {
            const int off = (kt + 1) * 32;
            const int nxt = ((kt + 1) & 1) * 4096;
            gld_lds16(A0 + off, smem + nxt + t * 8);
            gld_lds16(A1 + off, smem + nxt + 2048 + t * 8);
            gld_lds16(B0 + off, smem + 8192 + nxt + t * 8);
            gld_lds16(B1 + off, smem + 8192 + nxt + 2048 + t * 8);
        }
        const u16* as = smem + cur;
        const u16* bs = smem + 8192 + cur;
        bf16x8 af[4], bfv[4];
#pragma unroll
        for (int mi = 0; mi < 4; ++mi) {
            const int r = wm * 64 + mi * 16 + l15;
            af[mi] = ld_frag(as + (r * 4 + ((quad + (r >> 1)) & 3)) * 8);
        }
#pragma unroll
        for (int nj = 0; nj < 4; ++nj) {
            const int r = wn * 64 + nj * 16 + l15;
            bfv[nj] = ld_frag(bs + (r * 4 + ((quad + (r >> 1)) & 3)) * 8);
        }
#pragma unroll
        for (int mi = 0; mi < 4; ++mi)
#pragma unroll
            for (int nj = 0; nj < 4; ++nj)
                acc[mi][nj] = mfma16(af[mi], bfv[nj], acc[mi][nj]);
    }
#pragma unroll
    for (int mi = 0; mi < 4; ++mi)
#pragma unroll
        for (int nj = 0; nj < 4; ++nj) {
            const int n = n0 + wn * 64 + nj * 16 + l15;
            const float bv = bias[n];
#pragma unroll
            for (int r = 0; r < 4; ++r) {
                const int m = m0 + wm * 64 + mi * 16 + quad * 4 + r;
                C[(size_t)m * N + n] = acc[mi][nj][r] + bv;
            }
        }
}

// ---------------------------------------------------------------------------
// Flash attention, bf16 MFMA, softmax-lite (exp2 only, no max; additive
// split-K). Row sums via MFMA against ones (l = P @ 1).
// ---------------------------------------------------------------------------
__global__ __launch_bounds__(256, 4) void attn_mfma(const u16* __restrict__ Qb,
                                                    const u16* __restrict__ Kb,
                                                    const u16* __restrict__ Vt,
                                                    u16* __restrict__ Opart,
                                                    float* __restrict__ lpart) {
    __shared__ u16 Ks[64 * 64];
    __shared__ u16 Vs[64 * 64];
    __shared__ u16 Ps[128 * 72];
    const int t = threadIdx.x, lane = t & 63, w = t >> 6;
    const int l15 = lane & 15, quad = lane >> 4;
    const int bh = blockIdx.y;
    const int q0 = blockIdx.x * 128;
    const int z  = blockIdx.z;

    const int rowA = t >> 3, vA = t & 7;
    const int giA = (vA - rowA) & 7;
    const int rowB = rowA + 32;
    const int giB = (vA - rowB) & 7;

    const size_t kbase = (size_t)bh * SEQ * 64;   // Kb: [bh][n][d]
    const size_t vbase = (size_t)bh * 64 * SEQ;   // Vt: [bh][d][n]

    const uint4 ones_u = {0x3F803F80u, 0x3F803F80u, 0x3F803F80u, 0x3F803F80u};
    const bf16x8 onesf = __builtin_bit_cast(bf16x8, ones_u);

    bf16x8 aq[2][2];
#pragma unroll
    for (int mi = 0; mi < 2; ++mi)
#pragma unroll
        for (int ks = 0; ks < 2; ++ks)
            aq[mi][ks] = ld_frag(Qb + ((size_t)bh * SEQ + q0 + w * 32 + mi * 16 + l15) * 64
                                 + ks * 32 + quad * 8);

    f32x4 oacc[2][4] = {};
    f32x4 lacc[2] = {};

    for (int kt = 0; kt < 16; ++kt) {
        const int k0 = z * 1024 + kt * 64;
        __syncthreads();
        gld_lds16(Kb + kbase + (size_t)(k0 + rowA) * 64 + giA * 8, Ks + t * 8);
        gld_lds16(Kb + kbase + (size_t)(k0 + rowB) * 64 + giB * 8, Ks + 2048 + t * 8);
        gld_lds16(Vt + vbase + (size_t)rowA * SEQ + k0 + giA * 8, Vs + t * 8);
        gld_lds16(Vt + vbase + (size_t)rowB * SEQ + k0 + giB * 8, Vs + 2048 + t * 8);
        __syncthreads();

        // S^T = K Q^T : lane holds (q = l15, k = nk*16 + quad*4 + r)
        f32x4 sacc[2][4] = {};
#pragma unroll
        for (int ks = 0; ks < 2; ++ks)
#pragma unroll
            for (int nk = 0; nk < 4; ++nk) {
                const int rK = nk * 16 + l15;
                const bf16x8 kf = ld_frag(Ks + (rK * 8 + (((ks * 4 + quad) + rK) & 7)) * 8);
                sacc[0][nk] = mfma16(kf, aq[0][ks], sacc[0][nk]);
                sacc[1][nk] = mfma16(kf, aq[1][ks], sacc[1][nk]);
            }

        // softmax-lite: p = exp2(s); pack pairs and store P rows to LDS
#pragma unroll
        for (int mi = 0; mi < 2; ++mi) {
            const int prow = (w * 32 + mi * 16 + l15) * 72;
#pragma unroll
            for (int nk = 0; nk < 4; ++nk) {
                const float p0 = fexp2(sacc[mi][nk][0]);
                const float p1 = fexp2(sacc[mi][nk][1]);
                const float p2 = fexp2(sacc[mi][nk][2]);
                const float p3 = fexp2(sacc[mi][nk][3]);
                uint2 pk; pk.x = pkbf(p0, p1); pk.y = pkbf(p2, p3);
                *(uint2*)&Ps[prow + nk * 16 + quad * 4] = pk;
            }
        }

        // O += P V ; l += P @ ones  (same-wave LDS RAW: DS in-order per wave)
#pragma unroll
        for (int ks = 0; ks < 2; ++ks) {
            const bf16x8 ap0 = ld_frag(Ps + (w * 32 + l15) * 72 + ks * 32 + quad * 8);
            const bf16x8 ap1 = ld_frag(Ps + (w * 32 + 16 + l15) * 72 + ks * 32 + quad * 8);
            lacc[0] = mfma16(ap0, onesf, lacc[0]);
            lacc[1] = mfma16(ap1, onesf, lacc[1]);
#pragma unroll
            for (int nj = 0; nj < 4; ++nj) {
                const int rV = nj * 16 + l15;
                const bf16x8 vf = ld_frag(Vs + (rV * 8 + (((ks * 4 + quad) + rV) & 7)) * 8);
                oacc[0][nj] = mfma16(ap0, vf, oacc[0][nj]);
                oacc[1][nj] = mfma16(ap1, vf, oacc[1][nj]);
            }
        }
    }

    // epilogue: lacc is in C-layout (row = quad*4+r, col replicated)
#pragma unroll
    for (int mi = 0; mi < 2; ++mi)
#pragma unroll
        for (int r = 0; r < 4; ++r) {
            const int qrow = q0 + w * 32 + mi * 16 + quad * 4 + r;
            if (l15 == 0)
                lpart[((size_t)z * 32 + bh) * SEQ + qrow] = lacc[mi][r];
            const size_t orow = (((size_t)z * 32 + bh) * SEQ + qrow) * 64;
#pragma unroll
            for (int nj = 0; nj < 4; ++nj)
                Opart[orow + nj * 16 + l15] = f2bf(oacc[mi][nj][r]);
        }
}

// ---------------------------------------------------------------------------
// Merge the two K-splits: O = (O1 + O2) / (l1 + l2), repack to (B,N,H*DH) bf16.
// ---------------------------------------------------------------------------
__global__ __launch_bounds__(256) void merge_kernel(const u16* __restrict__ Opart,
                                                    const float* __restrict__ lpart,
                                                    u16* __restrict__ Ob) {
    const int gid = blockIdx.x * 256 + threadIdx.x;     // 1,048,576 total
    const int d4 = gid & 15, q = (gid >> 4) & 2047, bh = gid >> 15;
    const size_t i1 = ((size_t)bh * SEQ + q) * 64 + d4 * 4;
    const size_t i2 = i1 + (size_t)32 * SEQ * 64;
    const float inv = 1.0f / (lpart[(size_t)bh * SEQ + q] +
                              lpart[(size_t)(32 + bh) * SEQ + q]);
    const ushort4 a = *(const ushort4*)(Opart + i1);
    const ushort4 b = *(const ushort4*)(Opart + i2);
    ushort4 o;
    o.x = f2bf((bf2f(a.x) + bf2f(b.x)) * inv);
    o.y = f2bf((bf2f(a.y) + bf2f(b.y)) * inv);
    o.z = f2bf((bf2f(a.z) + bf2f(b.z)) * inv);
    o.w = f2bf((bf2f(a.w) + bf2f(b.w)) * inv);
    const int b_ = bh >> 4, h = bh & 15;
    *(ushort4*)(Ob + ((size_t)(b_ * SEQ + q)) * CH + h * 64 + d4 * 4) = o;
}

// ---------------------------------------------------------------------------
// Workspace layout (u16 offsets; extent 29,360,128 u16 = 56.00 MiB, proven):
//   [0         ..  4,194,304)  x_bf      -> attn_bf after qkv (merge out)
//   [4,194,304 ..  7,340,032)  wq_bf     -> lpart after qkv   (attn out)
//   [7,340,032 ..  8,388,608)  wp_bf     (live until proj)
//   [8,388,608 .. 12,582,912)  Qb
//   [12,582,912.. 16,777,216)  Kb
//   [16,777,216.. 20,971,520)  Vt
//   [20,971,520.. 29,360,128)  Opart; its first 16 KB doubles as tabq/tabk
//                              (tables dead before attn writes Opart)
// ---------------------------------------------------------------------------
extern "C" void kernel_launch(void* const* d_in, const int* in_sizes, int n_in,
                              void* d_out, int out_size, void* d_ws, size_t ws_size,
                              hipStream_t stream) {
    const float* x      = (const float*)d_in[0];
    const int*   pos    = (const int*)d_in[1];
    const float* qkv_w  = (const float*)d_in[2];
    const float* proj_w = (const float*)d_in[3];
    const float* proj_b = (const float*)d_in[4];
    float* out = (float*)d_out;

    u16* ws = (u16*)d_ws;
    u16* x_bf    = ws;
    u16* attn_bf = ws;                          // aliases x_bf (dead after qkv)
    u16* wq_bf   = ws + 4194304;
    float* lpart = (float*)(ws + 4194304);      // aliases wq_bf (dead after qkv)
    u16* wp_bf   = ws + 7340032;
    u16* Qb      = ws + 8388608;
    u16* Kb      = ws + 12582912;
    u16* Vt      = ws + 16777216;
    u16* Opart   = ws + 20971520;
    float2* tabq = (float2*)(ws + 20971520);    // aliases Opart head (dead by attn)
    float2* tabk = (float2*)(ws + 20971520 + 4096);

    const int M = BB * SEQ;  // 4096

    convert_kernel<<<8196, 256, 0, stream>>>(x, qkv_w, proj_w, x_bf, wq_bf, wp_bf,
                                             tabq, tabk);
    gemm_qkv_rope<<<dim3(3 * CH / 128, M / 128), 256, 0, stream>>>(
        x_bf, wq_bf, pos, tabq, tabk, Qb, Kb, Vt);
    attn_mfma<<<dim3(SEQ / 128, BB * NH, 2), 256, 0, stream>>>(Qb, Kb, Vt, Opart, lpart);
    merge_kernel<<<4096, 256, 0, stream>>>(Opart, lpart, attn_bf);
    gemm_bf16<<<dim3(CH / 128, M / 128), 256, 0, stream>>>(
        attn_bf, wp_bf, proj_b, out, M, CH, CH);
}